// Round 1
// baseline (1351.032 us; speedup 1.0000x reference)
//
#include <hip/hip_runtime.h>

// GCN: 3x (GEMM + normalized scatter-aggregate) + segment_max pool + linear.
// N=50000 nodes, E=800000 edges, H=128 feats, 64 graphs, 10 classes.

#define HID 128
#define NGRAPH 64
#define NCLS 10

__device__ __forceinline__ float atomAddF(float* p, float v) {
    return unsafeAtomicAdd(p, v);   // hw global_atomic_add_f32 on gfx950
}

// ---------- edge-weight L2 norm (sum of squares) ----------
__global__ void sumsq_kernel(const float* __restrict__ ew, int E, float* __restrict__ out) {
    float s = 0.f;
    for (int i = blockIdx.x * blockDim.x + threadIdx.x; i < E; i += gridDim.x * blockDim.x) {
        float v = ew[i];
        s += v * v;
    }
#pragma unroll
    for (int off = 32; off > 0; off >>= 1) s += __shfl_down(s, off, 64);
    __shared__ float red[4];
    int lane = threadIdx.x & 63;
    int wv = threadIdx.x >> 6;
    if (lane == 0) red[wv] = s;
    __syncthreads();
    if (threadIdx.x == 0) {
        float t = 0.f;
        int nw = blockDim.x >> 6;
        for (int w = 0; w < nw; ++w) t += red[w];
        atomicAdd(out, t);
    }
}

// ---------- raw (unnormalized) weighted in-degree ----------
__global__ void deg_kernel(const int* __restrict__ col, const float* __restrict__ ew,
                           int E, float* __restrict__ deg_raw) {
    int i = blockIdx.x * blockDim.x + threadIdx.x;
    if (i < E) atomAddF(&deg_raw[col[i]], ew[i]);
}

// ---------- dinv[i] = rsqrt(1 + deg_raw[i] * inv_norm) ----------
__global__ void dinv_kernel(const float* __restrict__ deg_raw, int n,
                            const float* __restrict__ sumsq, float* __restrict__ dinv) {
    int i = blockIdx.x * blockDim.x + threadIdx.x;
    if (i < n) {
        float inv = 1.f / fmaxf(sqrtf(*sumsq), 1e-12f);
        float d = 1.f + deg_raw[i] * inv;   // self-loop weight 1 + normalized in-weights
        dinv[i] = (d > 0.f) ? rsqrtf(d) : 0.f;
    }
}

// ---------- per-edge coefficient dinv[r]*w_hat*dinv[c] (shared by all 3 layers) ----------
__global__ void coef_kernel(const int* __restrict__ row, const int* __restrict__ col,
                            const float* __restrict__ ew, const float* __restrict__ dinv,
                            const float* __restrict__ sumsq, int E, float* __restrict__ coef) {
    int i = blockIdx.x * blockDim.x + threadIdx.x;
    if (i < E) {
        float inv = 1.f / fmaxf(sqrtf(*sumsq), 1e-12f);
        coef[i] = dinv[row[i]] * (ew[i] * inv) * dinv[col[i]];
    }
}

// ---------- GEMM: out[n][128] = (relu?)in[n][128] @ W[128][128] ----------
// 128 threads (one per out col), 8 rows per block, input rows staged in LDS.
template <bool RELU>
__global__ void gemm_kernel(const float* __restrict__ in, const float* __restrict__ W,
                            float* __restrict__ out, int n) {
    __shared__ float xs[8][HID];
    int r0 = blockIdx.x * 8;
    int f = threadIdx.x;
#pragma unroll
    for (int r = 0; r < 8; ++r) {
        int rr = r0 + r;
        float v = (rr < n) ? in[rr * HID + f] : 0.f;
        if (RELU) v = fmaxf(v, 0.f);
        xs[r][f] = v;
    }
    __syncthreads();
    float acc[8] = {0.f, 0.f, 0.f, 0.f, 0.f, 0.f, 0.f, 0.f};
    for (int k = 0; k < HID; ++k) {
        float w = W[k * HID + f];
#pragma unroll
        for (int r = 0; r < 8; ++r) acc[r] += xs[r][k] * w;
    }
#pragma unroll
    for (int r = 0; r < 8; ++r) {
        int rr = r0 + r;
        if (rr < n) out[rr * HID + f] = acc[r];
    }
}

// ---------- h[i][f] = b[f] + dinv[i]^2 * xw[i][f]  (bias + self-loop) ----------
__global__ void init_kernel(const float* __restrict__ xw, const float* __restrict__ dinv,
                            const float* __restrict__ b, float* __restrict__ h, int n) {
    int idx = blockIdx.x * blockDim.x + threadIdx.x;
    if (idx < n * HID) {
        int node = idx >> 7;
        int f = idx & (HID - 1);
        float di = dinv[node];
        h[idx] = b[f] + di * di * xw[idx];
    }
}

// ---------- scatter: h[col[e]][f] += coef[e] * xw[row[e]][f] ----------
// 256 threads = 2 edges/block, 128 feature-threads per edge.
__global__ void scatter_kernel(const int* __restrict__ row, const int* __restrict__ col,
                               const float* __restrict__ coef, const float* __restrict__ xw,
                               float* __restrict__ h, int E) {
    int e = blockIdx.x * 2 + (threadIdx.x >> 7);
    int f = threadIdx.x & (HID - 1);
    if (e < E) {
        float c = coef[e];
        int r = row[e], cl = col[e];
        atomAddF(&h[cl * HID + f], c * xw[r * HID + f]);
    }
}

// ---------- segment_max pool (relu fused: 0-init + max with raw h) ----------
// batch is sorted; block covers 64 consecutive nodes, flushes on graph change.
__global__ void pool_kernel(const float* __restrict__ h, const int* __restrict__ batch,
                            int n, unsigned* __restrict__ pooled) {
    int f = threadIdx.x;
    int n0 = blockIdx.x * 64;
    int n1 = min(n0 + 64, n);
    int cur = -1;
    float m = 0.f;
    for (int i = n0; i < n1; ++i) {
        int g = batch[i];
        if (g != cur) {
            if (cur >= 0) atomicMax(&pooled[cur * HID + f], __float_as_uint(m));
            cur = g;
            m = 0.f;
        }
        m = fmaxf(m, h[i * HID + f]);
    }
    if (cur >= 0) atomicMax(&pooled[cur * HID + f], __float_as_uint(m));
}

// ---------- final: out[g][c] = pooled[g] . Wl[:,c] + bl[c] ----------
__global__ void final_kernel(const unsigned* __restrict__ pooled, const float* __restrict__ Wl,
                             const float* __restrict__ bl, float* __restrict__ out) {
    __shared__ float p[HID];
    int g = blockIdx.x;
    p[threadIdx.x] = __uint_as_float(pooled[g * HID + threadIdx.x]);
    __syncthreads();
    if (threadIdx.x < NCLS) {
        float acc = bl[threadIdx.x];
        for (int f = 0; f < HID; ++f) acc += p[f] * Wl[f * NCLS + threadIdx.x];
        out[g * NCLS + threadIdx.x] = acc;
    }
}

extern "C" void kernel_launch(void* const* d_in, const int* in_sizes, int n_in,
                              void* d_out, int out_size, void* d_ws, size_t ws_size,
                              hipStream_t stream) {
    const float* x     = (const float*)d_in[0];
    const int*   ei    = (const int*)d_in[1];
    const float* ew    = (const float*)d_in[2];
    const int*   batch = (const int*)d_in[3];
    const float* W1 = (const float*)d_in[4];
    const float* b1 = (const float*)d_in[5];
    const float* W2 = (const float*)d_in[6];
    const float* b2 = (const float*)d_in[7];
    const float* W3 = (const float*)d_in[8];
    const float* b3 = (const float*)d_in[9];
    const float* Wl = (const float*)d_in[10];
    const float* bl = (const float*)d_in[11];

    const int E = in_sizes[2];
    const int n = in_sizes[3];
    const int* row = ei;
    const int* col = ei + E;

    float* ws = (float*)d_ws;
    size_t off = 0;
    float* sumsq   = ws + off; off += 64;        // scalar (padded for alignment)
    float* deg_raw = ws + off; off += (size_t)n;
    float* dinv    = ws + off; off += (size_t)n;
    float* coef    = ws + off; off += (size_t)E;
    float* bufA    = ws + off; off += (size_t)n * HID;  // xw scratch
    float* bufB    = ws + off; off += (size_t)n * HID;  // h ping-pong
    unsigned* pooled = (unsigned*)(ws + off); off += NGRAPH * HID;

    // zero-init accumulators (ws is poisoned with 0xAA each call)
    hipMemsetAsync(sumsq, 0, sizeof(float), stream);
    hipMemsetAsync(deg_raw, 0, (size_t)n * sizeof(float), stream);
    hipMemsetAsync(pooled, 0, NGRAPH * HID * sizeof(float), stream);

    // edge normalization (once; shared across the 3 conv layers)
    sumsq_kernel<<<512, 256, 0, stream>>>(ew, E, sumsq);
    deg_kernel<<<(E + 255) / 256, 256, 0, stream>>>(col, ew, E, deg_raw);
    dinv_kernel<<<(n + 255) / 256, 256, 0, stream>>>(deg_raw, n, sumsq, dinv);
    coef_kernel<<<(E + 255) / 256, 256, 0, stream>>>(row, col, ew, dinv, sumsq, E, coef);

    int gemm_grid = (n + 7) / 8;
    int init_grid = (n * HID + 255) / 256;
    int scat_grid = (E + 1) / 2;

    // layer 1: x -> bufA (xw) -> bufB (h1)
    gemm_kernel<false><<<gemm_grid, HID, 0, stream>>>(x, W1, bufA, n);
    init_kernel<<<init_grid, 256, 0, stream>>>(bufA, dinv, b1, bufB, n);
    scatter_kernel<<<scat_grid, 256, 0, stream>>>(row, col, coef, bufA, bufB, E);

    // layer 2: relu(bufB) -> bufA (xw) -> bufB (h2)
    gemm_kernel<true><<<gemm_grid, HID, 0, stream>>>(bufB, W2, bufA, n);
    init_kernel<<<init_grid, 256, 0, stream>>>(bufA, dinv, b2, bufB, n);
    scatter_kernel<<<scat_grid, 256, 0, stream>>>(row, col, coef, bufA, bufB, E);

    // layer 3: relu(bufB) -> bufA (xw) -> bufB (h3)
    gemm_kernel<true><<<gemm_grid, HID, 0, stream>>>(bufB, W3, bufA, n);
    init_kernel<<<init_grid, 256, 0, stream>>>(bufA, dinv, b3, bufB, n);
    scatter_kernel<<<scat_grid, 256, 0, stream>>>(row, col, coef, bufA, bufB, E);

    // pool (relu fused via 0-init) + head
    pool_kernel<<<(n + 63) / 64, HID, 0, stream>>>(bufB, batch, n, pooled);
    final_kernel<<<NGRAPH, HID, 0, stream>>>(pooled, Wl, bl, (float*)d_out);
}

// Round 2
// 632.772 us; speedup vs baseline: 2.1351x; 2.1351x over previous
//
#include <hip/hip_runtime.h>

// GCN: 3x (GEMM + CSR gather-aggregate) + segment_max pool + linear.
// N=50000 nodes, E=800000 edges, H=128 feats, 64 graphs, 10 classes.
// Round 2: atomic scatter -> on-device CSR (by destination) + register gather.

#define HID 128
#define NGRAPH 64
#define NCLS 10

__device__ __forceinline__ float atomAddF(float* p, float v) {
    return unsafeAtomicAdd(p, v);   // hw global_atomic_add_f32 on gfx950
}

// ---------- edge-weight L2 norm (sum of squares) ----------
__global__ void sumsq_kernel(const float* __restrict__ ew, int E, float* __restrict__ out) {
    float s = 0.f;
    for (int i = blockIdx.x * blockDim.x + threadIdx.x; i < E; i += gridDim.x * blockDim.x) {
        float v = ew[i];
        s += v * v;
    }
#pragma unroll
    for (int off = 32; off > 0; off >>= 1) s += __shfl_down(s, off, 64);
    __shared__ float red[4];
    int lane = threadIdx.x & 63;
    int wv = threadIdx.x >> 6;
    if (lane == 0) red[wv] = s;
    __syncthreads();
    if (threadIdx.x == 0) {
        float t = red[0] + red[1] + red[2] + red[3];
        atomicAdd(out, t);
    }
}

// ---------- per-destination edge count + weighted in-degree ----------
__global__ void hist_kernel(const int* __restrict__ col, const float* __restrict__ ew,
                            int E, int* __restrict__ cnt, float* __restrict__ degw) {
    int i = blockIdx.x * blockDim.x + threadIdx.x;
    if (i < E) {
        int c = col[i];
        atomicAdd(&cnt[c], 1);
        atomAddF(&degw[c], ew[i]);
    }
}

// ---------- dinv[i] = rsqrt(1 + degw[i] * inv_norm) ----------
__global__ void dinv_kernel(const float* __restrict__ degw, int n,
                            const float* __restrict__ sumsq, float* __restrict__ dinv) {
    int i = blockIdx.x * blockDim.x + threadIdx.x;
    if (i < n) {
        float inv = 1.f / fmaxf(sqrtf(*sumsq), 1e-12f);
        float d = 1.f + degw[i] * inv;   // self-loop weight 1 + normalized in-weights
        dinv[i] = (d > 0.f) ? rsqrtf(d) : 0.f;
    }
}

// ---------- 3-phase exclusive scan over cnt[0..n) -> rowptr ----------
__global__ void scan1_kernel(const int* __restrict__ cnt, int n,
                             int* __restrict__ partial, int* __restrict__ bsums) {
    __shared__ int tmp[256];
    int t = threadIdx.x;
    int i = blockIdx.x * 256 + t;
    int v = (i < n) ? cnt[i] : 0;
    tmp[t] = v;
    __syncthreads();
    for (int off = 1; off < 256; off <<= 1) {
        int u = (t >= off) ? tmp[t - off] : 0;
        __syncthreads();
        tmp[t] += u;
        __syncthreads();
    }
    if (i < n) partial[i] = tmp[t] - v;   // exclusive within block
    if (t == 255) bsums[blockIdx.x] = tmp[255];
}

__global__ void scan2_kernel(int* __restrict__ bsums, int nb) {
    __shared__ int tmp[256];
    int t = threadIdx.x;
    int v = (t < nb) ? bsums[t] : 0;
    tmp[t] = v;
    __syncthreads();
    for (int off = 1; off < 256; off <<= 1) {
        int u = (t >= off) ? tmp[t - off] : 0;
        __syncthreads();
        tmp[t] += u;
        __syncthreads();
    }
    if (t < nb) bsums[t] = tmp[t] - v;    // exclusive block offsets
}

__global__ void scan3_kernel(const int* __restrict__ partial, const int* __restrict__ bsums,
                             int* __restrict__ rowptr, int* __restrict__ cursor, int n, int E) {
    int i = blockIdx.x * 256 + threadIdx.x;
    if (i < n) {
        int v = partial[i] + bsums[blockIdx.x];
        rowptr[i] = v;
        cursor[i] = v;
    }
    if (i == 0) rowptr[n] = E;
}

// ---------- bucket-scatter edges to CSR slots; coef excludes dinv[col] ----------
__global__ void build_csr_kernel(const int* __restrict__ row, const int* __restrict__ col,
                                 const float* __restrict__ ew, const float* __restrict__ dinv,
                                 const float* __restrict__ sumsq, int* __restrict__ cursor,
                                 int* __restrict__ ssrc, float* __restrict__ scoef, int E) {
    int e = blockIdx.x * blockDim.x + threadIdx.x;
    if (e < E) {
        float inv = 1.f / fmaxf(sqrtf(*sumsq), 1e-12f);
        int c = col[e], r = row[e];
        int pos = atomicAdd(&cursor[c], 1);
        ssrc[pos] = r;
        scoef[pos] = dinv[r] * (ew[e] * inv);
    }
}

// ---------- GEMM: out[n][128] = (relu?)in[n][128] @ W[128][128] ----------
// W staged in LDS (64KB), 64-row x tile (32KB). 256 thr: 32 col-threads
// (4 cols each: f, f+32, f+64, f+96) x 8 row-groups (8 rows each). VALU-bound.
template <bool RELU>
__global__ __launch_bounds__(256, 1) void gemm_kernel(const float* __restrict__ in,
                                                      const float* __restrict__ W,
                                                      float* __restrict__ out, int n) {
    __shared__ float Wl[HID * HID];   // 64 KB
    __shared__ float xs[64][HID];     // 32 KB
    const float4* W4 = (const float4*)W;
    float4* Wl4 = (float4*)Wl;
#pragma unroll
    for (int i = 0; i < 16; ++i) Wl4[threadIdx.x + i * 256] = W4[threadIdx.x + i * 256];
    int r0 = blockIdx.x * 64;
    const float4* in4 = (const float4*)in;
    float4* xs4 = (float4*)xs;
#pragma unroll
    for (int i = 0; i < 8; ++i) {     // 64 rows x 32 q = 2048 float4
        int idx = threadIdx.x + i * 256;
        int rr = r0 + (idx >> 5);
        float4 v = make_float4(0.f, 0.f, 0.f, 0.f);
        if (rr < n) v = in4[(size_t)rr * 32 + (idx & 31)];
        if (RELU) {
            v.x = fmaxf(v.x, 0.f); v.y = fmaxf(v.y, 0.f);
            v.z = fmaxf(v.z, 0.f); v.w = fmaxf(v.w, 0.f);
        }
        xs4[idx] = v;
    }
    __syncthreads();
    int f = threadIdx.x & 31;
    int rg = (threadIdx.x >> 5) * 8;
    float acc[4][8];
#pragma unroll
    for (int c = 0; c < 4; ++c)
#pragma unroll
        for (int r = 0; r < 8; ++r) acc[c][r] = 0.f;
    for (int k = 0; k < HID; k += 4) {
        float w[4][4];
#pragma unroll
        for (int kk = 0; kk < 4; ++kk)
#pragma unroll
            for (int c = 0; c < 4; ++c) w[c][kk] = Wl[(k + kk) * HID + f + c * 32];
#pragma unroll
        for (int r = 0; r < 8; ++r) {
            float4 xv = *(const float4*)&xs[rg + r][k];
#pragma unroll
            for (int c = 0; c < 4; ++c)
                acc[c][r] += xv.x * w[c][0] + xv.y * w[c][1] + xv.z * w[c][2] + xv.w * w[c][3];
        }
    }
#pragma unroll
    for (int r = 0; r < 8; ++r) {
        int rr = r0 + rg + r;
        if (rr < n) {
#pragma unroll
            for (int c = 0; c < 4; ++c) out[(size_t)rr * HID + f + c * 32] = acc[c][r];
        }
    }
}

// ---------- gather: h[c] = b + dinv[c]*(dinv[c]*xw[c] + sum_e scoef[e]*xw[src[e]]) ----------
// 32 threads per node (float4 per thread), 8 nodes per 256-block. One write per row.
__global__ void gather_kernel(const int* __restrict__ rowptr, const int* __restrict__ ssrc,
                              const float* __restrict__ scoef, const float* __restrict__ xw,
                              const float* __restrict__ dinv, const float* __restrict__ bias,
                              float* __restrict__ h, int n) {
    int node = blockIdx.x * 8 + (threadIdx.x >> 5);
    if (node >= n) return;
    int q = threadIdx.x & 31;
    const float4* xw4 = (const float4*)xw;
    float dc = dinv[node];
    float4 a = xw4[node * 32 + q];
    float4 acc = make_float4(dc * a.x, dc * a.y, dc * a.z, dc * a.w);
    int s = rowptr[node], e = rowptr[node + 1];
    int i = s;
    for (; i + 1 < e; i += 2) {
        int r0 = ssrc[i], r1 = ssrc[i + 1];
        float c0 = scoef[i], c1 = scoef[i + 1];
        float4 v0 = xw4[r0 * 32 + q];
        float4 v1 = xw4[r1 * 32 + q];
        acc.x += c0 * v0.x + c1 * v1.x;
        acc.y += c0 * v0.y + c1 * v1.y;
        acc.z += c0 * v0.z + c1 * v1.z;
        acc.w += c0 * v0.w + c1 * v1.w;
    }
    if (i < e) {
        int r = ssrc[i];
        float c = scoef[i];
        float4 v = xw4[r * 32 + q];
        acc.x += c * v.x; acc.y += c * v.y; acc.z += c * v.z; acc.w += c * v.w;
    }
    float4 bb = ((const float4*)bias)[q];
    float4 o = make_float4(bb.x + dc * acc.x, bb.y + dc * acc.y,
                           bb.z + dc * acc.z, bb.w + dc * acc.w);
    ((float4*)h)[node * 32 + q] = o;
}

// ---------- segment_max pool (relu fused: 0-init + max with raw h) ----------
__global__ void pool_kernel(const float* __restrict__ h, const int* __restrict__ batch,
                            int n, unsigned* __restrict__ pooled) {
    int f = threadIdx.x;
    int n0 = blockIdx.x * 64;
    int n1 = min(n0 + 64, n);
    int cur = -1;
    float m = 0.f;
    for (int i = n0; i < n1; ++i) {
        int g = batch[i];
        if (g != cur) {
            if (cur >= 0) atomicMax(&pooled[cur * HID + f], __float_as_uint(m));
            cur = g;
            m = 0.f;
        }
        m = fmaxf(m, h[i * HID + f]);
    }
    if (cur >= 0) atomicMax(&pooled[cur * HID + f], __float_as_uint(m));
}

// ---------- final: out[g][c] = pooled[g] . Wl[:,c] + bl[c] ----------
__global__ void final_kernel(const unsigned* __restrict__ pooled, const float* __restrict__ Wl,
                             const float* __restrict__ bl, float* __restrict__ out) {
    __shared__ float p[HID];
    int g = blockIdx.x;
    p[threadIdx.x] = __uint_as_float(pooled[g * HID + threadIdx.x]);
    __syncthreads();
    if (threadIdx.x < NCLS) {
        float acc = bl[threadIdx.x];
        for (int f = 0; f < HID; ++f) acc += p[f] * Wl[f * NCLS + threadIdx.x];
        out[g * NCLS + threadIdx.x] = acc;
    }
}

extern "C" void kernel_launch(void* const* d_in, const int* in_sizes, int n_in,
                              void* d_out, int out_size, void* d_ws, size_t ws_size,
                              hipStream_t stream) {
    const float* x     = (const float*)d_in[0];
    const int*   ei    = (const int*)d_in[1];
    const float* ew    = (const float*)d_in[2];
    const int*   batch = (const int*)d_in[3];
    const float* W1 = (const float*)d_in[4];
    const float* b1 = (const float*)d_in[5];
    const float* W2 = (const float*)d_in[6];
    const float* b2 = (const float*)d_in[7];
    const float* W3 = (const float*)d_in[8];
    const float* b3 = (const float*)d_in[9];
    const float* Wl = (const float*)d_in[10];
    const float* bl = (const float*)d_in[11];

    const int E = in_sizes[2];
    const int n = in_sizes[3];
    const int* row = ei;
    const int* col = ei + E;
    const int npad = 50048;              // n rounded up to 64

    float* ws = (float*)d_ws;
    size_t off = 0;
    float* sumsq = ws + off; off += 64;
    float* degw  = ws + off; off += npad;
    float* dinv  = ws + off; off += npad;
    int*   cnt   = (int*)(ws + off); off += npad;     // reused as cursor after scan
    int*   rowptr= (int*)(ws + off); off += npad + 64;
    int*   bsums = (int*)(ws + off); off += 512;
    int*   ssrc  = (int*)(ws + off); off += (size_t)E;
    float* scoef = ws + off; off += (size_t)E;
    float* bufA  = ws + off; off += (size_t)n * HID;  // xw scratch (also scan 'partial')
    float* bufB  = ws + off; off += (size_t)n * HID;  // h ping-pong
    unsigned* pooled = (unsigned*)(ws + off); off += NGRAPH * HID;
    int* partial = (int*)bufA;            // alias: scan completes before first GEMM

    hipMemsetAsync(sumsq, 0, sizeof(float), stream);
    hipMemsetAsync(degw, 0, (size_t)n * sizeof(float), stream);
    hipMemsetAsync(cnt, 0, (size_t)n * sizeof(int), stream);
    hipMemsetAsync(pooled, 0, NGRAPH * HID * sizeof(float), stream);

    const int nb = (n + 255) / 256;       // 196 blocks
    const int eg = (E + 255) / 256;

    sumsq_kernel<<<512, 256, 0, stream>>>(ew, E, sumsq);
    hist_kernel<<<eg, 256, 0, stream>>>(col, ew, E, cnt, degw);
    dinv_kernel<<<nb, 256, 0, stream>>>(degw, n, sumsq, dinv);
    scan1_kernel<<<nb, 256, 0, stream>>>(cnt, n, partial, bsums);
    scan2_kernel<<<1, 256, 0, stream>>>(bsums, nb);
    scan3_kernel<<<nb, 256, 0, stream>>>(partial, bsums, rowptr, cnt /*cursor*/, n, E);
    build_csr_kernel<<<eg, 256, 0, stream>>>(row, col, ew, dinv, sumsq, cnt /*cursor*/,
                                             ssrc, scoef, E);

    const int gemm_grid = (n + 63) / 64;
    const int gath_grid = (n + 7) / 8;

    // layer 1
    gemm_kernel<false><<<gemm_grid, 256, 0, stream>>>(x, W1, bufA, n);
    gather_kernel<<<gath_grid, 256, 0, stream>>>(rowptr, ssrc, scoef, bufA, dinv, b1, bufB, n);
    // layer 2
    gemm_kernel<true><<<gemm_grid, 256, 0, stream>>>(bufB, W2, bufA, n);
    gather_kernel<<<gath_grid, 256, 0, stream>>>(rowptr, ssrc, scoef, bufA, dinv, b2, bufB, n);
    // layer 3
    gemm_kernel<true><<<gemm_grid, 256, 0, stream>>>(bufB, W3, bufA, n);
    gather_kernel<<<gath_grid, 256, 0, stream>>>(rowptr, ssrc, scoef, bufA, dinv, b3, bufB, n);

    // pool (relu fused via 0-init) + head
    pool_kernel<<<(n + 63) / 64, HID, 0, stream>>>(bufB, batch, n, pooled);
    final_kernel<<<NGRAPH, HID, 0, stream>>>(pooled, Wl, bl, (float*)d_out);
}

// Round 3
// 507.364 us; speedup vs baseline: 2.6628x; 1.2472x over previous
//
#include <hip/hip_runtime.h>

// GCN: 3x (GEMM + CSR gather-aggregate) + segment_max pool + linear.
// Round 3: GEMM 64-col split (65KB LDS -> 2 blocks/CU); hist counts only,
// degree summed from CSR slices (no float atomics); 4-deep gather unroll.

#define HID 128
#define NGRAPH 64
#define NCLS 10

// ---------- edge-weight L2 norm (sum of squares) ----------
__global__ void sumsq_kernel(const float* __restrict__ ew, int E, float* __restrict__ out) {
    float s = 0.f;
    for (int i = blockIdx.x * blockDim.x + threadIdx.x; i < E; i += gridDim.x * blockDim.x) {
        float v = ew[i];
        s += v * v;
    }
#pragma unroll
    for (int off = 32; off > 0; off >>= 1) s += __shfl_down(s, off, 64);
    __shared__ float red[4];
    int lane = threadIdx.x & 63;
    int wv = threadIdx.x >> 6;
    if (lane == 0) red[wv] = s;
    __syncthreads();
    if (threadIdx.x == 0) {
        float t = red[0] + red[1] + red[2] + red[3];
        atomicAdd(out, t);
    }
}

// ---------- per-destination edge count (int atomics only) ----------
__global__ void hist_kernel(const int* __restrict__ col, int E, int* __restrict__ cnt) {
    int i = blockIdx.x * blockDim.x + threadIdx.x;
    if (i < E) atomicAdd(&cnt[col[i]], 1);
}

// ---------- 3-phase exclusive scan over cnt[0..n) -> rowptr ----------
__global__ void scan1_kernel(const int* __restrict__ cnt, int n,
                             int* __restrict__ partial, int* __restrict__ bsums) {
    __shared__ int tmp[256];
    int t = threadIdx.x;
    int i = blockIdx.x * 256 + t;
    int v = (i < n) ? cnt[i] : 0;
    tmp[t] = v;
    __syncthreads();
    for (int off = 1; off < 256; off <<= 1) {
        int u = (t >= off) ? tmp[t - off] : 0;
        __syncthreads();
        tmp[t] += u;
        __syncthreads();
    }
    if (i < n) partial[i] = tmp[t] - v;
    if (t == 255) bsums[blockIdx.x] = tmp[255];
}

__global__ void scan2_kernel(int* __restrict__ bsums, int nb) {
    __shared__ int tmp[256];
    int t = threadIdx.x;
    int v = (t < nb) ? bsums[t] : 0;
    tmp[t] = v;
    __syncthreads();
    for (int off = 1; off < 256; off <<= 1) {
        int u = (t >= off) ? tmp[t - off] : 0;
        __syncthreads();
        tmp[t] += u;
        __syncthreads();
    }
    if (t < nb) bsums[t] = tmp[t] - v;
}

__global__ void scan3_kernel(const int* __restrict__ partial, const int* __restrict__ bsums,
                             int* __restrict__ rowptr, int* __restrict__ cursor, int n, int E) {
    int i = blockIdx.x * 256 + threadIdx.x;
    if (i < n) {
        int v = partial[i] + bsums[blockIdx.x];
        rowptr[i] = v;
        cursor[i] = v;
    }
    if (i == 0) rowptr[n] = E;
}

// ---------- bucket-scatter edges; scoef holds RAW ew for now ----------
__global__ void build_csr_kernel(const int* __restrict__ row, const int* __restrict__ col,
                                 const float* __restrict__ ew, int* __restrict__ cursor,
                                 int* __restrict__ ssrc, float* __restrict__ scoef, int E) {
    int e = blockIdx.x * blockDim.x + threadIdx.x;
    if (e < E) {
        int pos = atomicAdd(&cursor[col[e]], 1);
        ssrc[pos] = row[e];
        scoef[pos] = ew[e];
    }
}

// ---------- dinv[i] from CSR slice sum (no atomics); 4 lanes/node ----------
__global__ void dinv_kernel(const int* __restrict__ rowptr, const float* __restrict__ scoef,
                            const float* __restrict__ sumsq, float* __restrict__ dinv, int n) {
    int t = blockIdx.x * blockDim.x + threadIdx.x;
    int node = t >> 2, lane = t & 3;
    if (node >= n) return;
    int s = rowptr[node], e = rowptr[node + 1];
    float sum = 0.f;
    for (int i = s + lane; i < e; i += 4) sum += scoef[i];
    sum += __shfl_xor(sum, 1, 64);
    sum += __shfl_xor(sum, 2, 64);
    if (lane == 0) {
        float inv = 1.f / fmaxf(sqrtf(*sumsq), 1e-12f);
        float d = 1.f + sum * inv;      // self-loop weight 1 + normalized in-weights
        dinv[node] = (d > 0.f) ? rsqrtf(d) : 0.f;
    }
}

// ---------- finalize scoef[i] = dinv[src] * ew_hat (in place) ----------
__global__ void coef_kernel(const int* __restrict__ ssrc, const float* __restrict__ dinv,
                            const float* __restrict__ sumsq, float* __restrict__ scoef, int E) {
    int i = blockIdx.x * blockDim.x + threadIdx.x;
    if (i < E) {
        float inv = 1.f / fmaxf(sqrtf(*sumsq), 1e-12f);
        scoef[i] = dinv[ssrc[i]] * (scoef[i] * inv);
    }
}

// ---------- GEMM: out[n][128] = (relu?)in[n][128] @ W[128][128] ----------
// Block: 64 rows x 64 cols (col half ch). LDS 65KB -> 2 blocks/CU.
// 256 thr = 16 col-groups x 16 row-groups, 4x4 micro-tile each.
template <bool RELU>
__global__ __launch_bounds__(256, 2) void gemm_kernel(const float* __restrict__ in,
                                                      const float* __restrict__ W,
                                                      float* __restrict__ out, int n) {
    __shared__ float xs[64 * 132];   // padded stride 132 -> <=2-way banks
    __shared__ float wl[128 * 64];
    const int rt = blockIdx.x >> 1;
    const int ch = blockIdx.x & 1;
    const int r0 = rt * 64;
    const float4* in4 = (const float4*)in;
    const float4* W4 = (const float4*)W;
#pragma unroll
    for (int i = 0; i < 8; ++i) {
        int idx = threadIdx.x + i * 256;        // 0..2047
        int r = idx >> 5, q = idx & 31;
        float4 v = make_float4(0.f, 0.f, 0.f, 0.f);
        int rr = r0 + r;
        if (rr < n) v = in4[(size_t)rr * 32 + q];
        if (RELU) {
            v.x = fmaxf(v.x, 0.f); v.y = fmaxf(v.y, 0.f);
            v.z = fmaxf(v.z, 0.f); v.w = fmaxf(v.w, 0.f);
        }
        *(float4*)&xs[r * 132 + q * 4] = v;
        int k = idx >> 4, q2 = idx & 15;
        *(float4*)&wl[k * 64 + q2 * 4] = W4[(size_t)k * 32 + ch * 16 + q2];
    }
    __syncthreads();
    const int tx = threadIdx.x & 15;   // col group (4 cols)
    const int ty = threadIdx.x >> 4;   // row group (4 rows)
    float acc[4][4];
#pragma unroll
    for (int r = 0; r < 4; ++r)
#pragma unroll
        for (int c = 0; c < 4; ++c) acc[r][c] = 0.f;
    for (int k = 0; k < HID; k += 4) {
        float4 xv[4], wv[4];
#pragma unroll
        for (int r = 0; r < 4; ++r) xv[r] = *(const float4*)&xs[(ty * 4 + r) * 132 + k];
#pragma unroll
        for (int kk = 0; kk < 4; ++kk) wv[kk] = *(const float4*)&wl[(k + kk) * 64 + tx * 4];
#pragma unroll
        for (int r = 0; r < 4; ++r) {
            const float* xr = (const float*)&xv[r];
#pragma unroll
            for (int c = 0; c < 4; ++c) {
                acc[r][c] += xr[0] * ((const float*)&wv[0])[c]
                           + xr[1] * ((const float*)&wv[1])[c]
                           + xr[2] * ((const float*)&wv[2])[c]
                           + xr[3] * ((const float*)&wv[3])[c];
            }
        }
    }
#pragma unroll
    for (int r = 0; r < 4; ++r) {
        int rr = r0 + ty * 4 + r;
        if (rr < n) {
            float4 o = make_float4(acc[r][0], acc[r][1], acc[r][2], acc[r][3]);
            *(float4*)&out[(size_t)rr * HID + ch * 64 + tx * 4] = o;
        }
    }
}

// ---------- gather: h[c] = b + dinv[c]*(dinv[c]*xw[c] + sum_e scoef[e]*xw[src[e]]) ----------
// 32 threads per node (float4 each), 8 nodes per 256-block, 4-deep edge unroll.
__global__ void gather_kernel(const int* __restrict__ rowptr, const int* __restrict__ ssrc,
                              const float* __restrict__ scoef, const float* __restrict__ xw,
                              const float* __restrict__ dinv, const float* __restrict__ bias,
                              float* __restrict__ h, int n) {
    int node = blockIdx.x * 8 + (threadIdx.x >> 5);
    if (node >= n) return;
    int q = threadIdx.x & 31;
    const float4* xw4 = (const float4*)xw;
    float dc = dinv[node];
    float4 a = xw4[(size_t)node * 32 + q];
    float4 acc = make_float4(dc * a.x, dc * a.y, dc * a.z, dc * a.w);
    int s = rowptr[node], e = rowptr[node + 1];
    int i = s;
    for (; i + 3 < e; i += 4) {
        int r0 = ssrc[i], r1 = ssrc[i + 1], r2 = ssrc[i + 2], r3 = ssrc[i + 3];
        float c0 = scoef[i], c1 = scoef[i + 1], c2 = scoef[i + 2], c3 = scoef[i + 3];
        float4 v0 = xw4[(size_t)r0 * 32 + q];
        float4 v1 = xw4[(size_t)r1 * 32 + q];
        float4 v2 = xw4[(size_t)r2 * 32 + q];
        float4 v3 = xw4[(size_t)r3 * 32 + q];
        acc.x += c0 * v0.x + c1 * v1.x + c2 * v2.x + c3 * v3.x;
        acc.y += c0 * v0.y + c1 * v1.y + c2 * v2.y + c3 * v3.y;
        acc.z += c0 * v0.z + c1 * v1.z + c2 * v2.z + c3 * v3.z;
        acc.w += c0 * v0.w + c1 * v1.w + c2 * v2.w + c3 * v3.w;
    }
    for (; i < e; ++i) {
        int r = ssrc[i];
        float c = scoef[i];
        float4 v = xw4[(size_t)r * 32 + q];
        acc.x += c * v.x; acc.y += c * v.y; acc.z += c * v.z; acc.w += c * v.w;
    }
    float4 bb = ((const float4*)bias)[q];
    float4 o = make_float4(bb.x + dc * acc.x, bb.y + dc * acc.y,
                           bb.z + dc * acc.z, bb.w + dc * acc.w);
    ((float4*)h)[(size_t)node * 32 + q] = o;
}

// ---------- segment_max pool (relu fused: 0-init + max with raw h) ----------
__global__ void pool_kernel(const float* __restrict__ h, const int* __restrict__ batch,
                            int n, unsigned* __restrict__ pooled) {
    int f = threadIdx.x;
    int n0 = blockIdx.x * 64;
    int n1 = min(n0 + 64, n);
    int cur = -1;
    float m = 0.f;
    for (int i = n0; i < n1; ++i) {
        int g = batch[i];
        if (g != cur) {
            if (cur >= 0) atomicMax(&pooled[cur * HID + f], __float_as_uint(m));
            cur = g;
            m = 0.f;
        }
        m = fmaxf(m, h[i * HID + f]);
    }
    if (cur >= 0) atomicMax(&pooled[cur * HID + f], __float_as_uint(m));
}

// ---------- final: out[g][c] = pooled[g] . Wl[:,c] + bl[c] ----------
__global__ void final_kernel(const unsigned* __restrict__ pooled, const float* __restrict__ Wl,
                             const float* __restrict__ bl, float* __restrict__ out) {
    __shared__ float p[HID];
    int g = blockIdx.x;
    p[threadIdx.x] = __uint_as_float(pooled[g * HID + threadIdx.x]);
    __syncthreads();
    if (threadIdx.x < NCLS) {
        float acc = bl[threadIdx.x];
        for (int f = 0; f < HID; ++f) acc += p[f] * Wl[f * NCLS + threadIdx.x];
        out[g * NCLS + threadIdx.x] = acc;
    }
}

extern "C" void kernel_launch(void* const* d_in, const int* in_sizes, int n_in,
                              void* d_out, int out_size, void* d_ws, size_t ws_size,
                              hipStream_t stream) {
    const float* x     = (const float*)d_in[0];
    const int*   ei    = (const int*)d_in[1];
    const float* ew    = (const float*)d_in[2];
    const int*   batch = (const int*)d_in[3];
    const float* W1 = (const float*)d_in[4];
    const float* b1 = (const float*)d_in[5];
    const float* W2 = (const float*)d_in[6];
    const float* b2 = (const float*)d_in[7];
    const float* W3 = (const float*)d_in[8];
    const float* b3 = (const float*)d_in[9];
    const float* Wl = (const float*)d_in[10];
    const float* bl = (const float*)d_in[11];

    const int E = in_sizes[2];
    const int n = in_sizes[3];
    const int* row = ei;
    const int* col = ei + E;
    const int npad = 50048;

    float* ws = (float*)d_ws;
    size_t off = 0;
    float* sumsq = ws + off; off += 64;
    float* dinv  = ws + off; off += npad;
    int*   cnt   = (int*)(ws + off); off += npad;     // reused as cursor after scan
    int*   rowptr= (int*)(ws + off); off += npad + 64;
    int*   bsums = (int*)(ws + off); off += 512;
    int*   ssrc  = (int*)(ws + off); off += (size_t)E;
    float* scoef = ws + off; off += (size_t)E;
    float* bufA  = ws + off; off += (size_t)n * HID;  // xw scratch (aliases scan 'partial')
    float* bufB  = ws + off; off += (size_t)n * HID;  // h ping-pong
    unsigned* pooled = (unsigned*)(ws + off); off += NGRAPH * HID;
    int* partial = (int*)bufA;   // scan completes before first GEMM writes bufA

    hipMemsetAsync(sumsq, 0, sizeof(float), stream);
    hipMemsetAsync(cnt, 0, (size_t)n * sizeof(int), stream);
    hipMemsetAsync(pooled, 0, NGRAPH * HID * sizeof(float), stream);

    const int nb = (n + 255) / 256;
    const int eg = (E + 255) / 256;

    sumsq_kernel<<<512, 256, 0, stream>>>(ew, E, sumsq);
    hist_kernel<<<eg, 256, 0, stream>>>(col, E, cnt);
    scan1_kernel<<<nb, 256, 0, stream>>>(cnt, n, partial, bsums);
    scan2_kernel<<<1, 256, 0, stream>>>(bsums, nb);
    scan3_kernel<<<nb, 256, 0, stream>>>(partial, bsums, rowptr, cnt /*cursor*/, n, E);
    build_csr_kernel<<<eg, 256, 0, stream>>>(row, col, ew, cnt /*cursor*/, ssrc, scoef, E);
    dinv_kernel<<<(4 * n + 255) / 256, 256, 0, stream>>>(rowptr, scoef, sumsq, dinv, n);
    coef_kernel<<<eg, 256, 0, stream>>>(ssrc, dinv, sumsq, scoef, E);

    const int gemm_grid = ((n + 63) / 64) * 2;
    const int gath_grid = (n + 7) / 8;

    // layer 1
    gemm_kernel<false><<<gemm_grid, 256, 0, stream>>>(x, W1, bufA, n);
    gather_kernel<<<gath_grid, 256, 0, stream>>>(rowptr, ssrc, scoef, bufA, dinv, b1, bufB, n);
    // layer 2
    gemm_kernel<true><<<gemm_grid, 256, 0, stream>>>(bufB, W2, bufA, n);
    gather_kernel<<<gath_grid, 256, 0, stream>>>(rowptr, ssrc, scoef, bufA, dinv, b2, bufB, n);
    // layer 3
    gemm_kernel<true><<<gemm_grid, 256, 0, stream>>>(bufB, W3, bufA, n);
    gather_kernel<<<gath_grid, 256, 0, stream>>>(rowptr, ssrc, scoef, bufA, dinv, b3, bufB, n);

    // pool (relu fused via 0-init) + head
    pool_kernel<<<(n + 63) / 64, HID, 0, stream>>>(bufB, batch, n, pooled);
    final_kernel<<<NGRAPH, HID, 0, stream>>>(pooled, Wl, bl, (float*)d_out);
}

// Round 4
// 445.476 us; speedup vs baseline: 3.0328x; 1.1389x over previous
//
#include <hip/hip_runtime.h>

// GCN: 3x (GEMM + CSR gather-aggregate) + segment_max pool + linear.
// Round 4: xw stored bf16 (halves gather traffic; threshold is bf16-scale),
// CSR edges packed as int2 (one 8B scattered store per edge).

#define HID 128
#define NGRAPH 64
#define NCLS 10

typedef unsigned int uint;
typedef unsigned short ushort;

// pack two f32 -> bf16x2 (RNE)
__device__ __forceinline__ uint pack_bf2(float a, float b) {
    uint ua = __float_as_uint(a), ub = __float_as_uint(b);
    ua = (ua + 0x7fffu + ((ua >> 16) & 1u)) >> 16;
    ub = (ub + 0x7fffu + ((ub >> 16) & 1u)) & 0xffff0000u;
    return ua | ub;
}
__device__ __forceinline__ float bf_lo(uint u) { return __uint_as_float(u << 16); }
__device__ __forceinline__ float bf_hi(uint u) { return __uint_as_float(u & 0xffff0000u); }

// ---------- edge-weight L2 norm (sum of squares) ----------
__global__ void sumsq_kernel(const float* __restrict__ ew, int E, float* __restrict__ out) {
    float s = 0.f;
    for (int i = blockIdx.x * blockDim.x + threadIdx.x; i < E; i += gridDim.x * blockDim.x) {
        float v = ew[i];
        s += v * v;
    }
#pragma unroll
    for (int off = 32; off > 0; off >>= 1) s += __shfl_down(s, off, 64);
    __shared__ float red[4];
    int lane = threadIdx.x & 63;
    int wv = threadIdx.x >> 6;
    if (lane == 0) red[wv] = s;
    __syncthreads();
    if (threadIdx.x == 0) {
        float t = red[0] + red[1] + red[2] + red[3];
        atomicAdd(out, t);
    }
}

// ---------- per-destination edge count ----------
__global__ void hist_kernel(const int* __restrict__ col, int E, int* __restrict__ cnt) {
    int i = blockIdx.x * blockDim.x + threadIdx.x;
    if (i < E) atomicAdd(&cnt[col[i]], 1);
}

// ---------- 3-phase exclusive scan over cnt[0..n) -> rowptr ----------
__global__ void scan1_kernel(const int* __restrict__ cnt, int n,
                             int* __restrict__ partial, int* __restrict__ bsums) {
    __shared__ int tmp[256];
    int t = threadIdx.x;
    int i = blockIdx.x * 256 + t;
    int v = (i < n) ? cnt[i] : 0;
    tmp[t] = v;
    __syncthreads();
    for (int off = 1; off < 256; off <<= 1) {
        int u = (t >= off) ? tmp[t - off] : 0;
        __syncthreads();
        tmp[t] += u;
        __syncthreads();
    }
    if (i < n) partial[i] = tmp[t] - v;
    if (t == 255) bsums[blockIdx.x] = tmp[255];
}

__global__ void scan2_kernel(int* __restrict__ bsums, int nb) {
    __shared__ int tmp[256];
    int t = threadIdx.x;
    int v = (t < nb) ? bsums[t] : 0;
    tmp[t] = v;
    __syncthreads();
    for (int off = 1; off < 256; off <<= 1) {
        int u = (t >= off) ? tmp[t - off] : 0;
        __syncthreads();
        tmp[t] += u;
        __syncthreads();
    }
    if (t < nb) bsums[t] = tmp[t] - v;
}

__global__ void scan3_kernel(const int* __restrict__ partial, const int* __restrict__ bsums,
                             int* __restrict__ rowptr, int* __restrict__ cursor, int n, int E) {
    int i = blockIdx.x * 256 + threadIdx.x;
    if (i < n) {
        int v = partial[i] + bsums[blockIdx.x];
        rowptr[i] = v;
        cursor[i] = v;
    }
    if (i == 0) rowptr[n] = E;
}

// ---------- bucket-scatter edges: eds[pos] = {src, raw ew} (one 8B store) ----------
__global__ void build_csr_kernel(const int* __restrict__ row, const int* __restrict__ col,
                                 const float* __restrict__ ew, int* __restrict__ cursor,
                                 int2* __restrict__ eds, int E) {
    int e = blockIdx.x * blockDim.x + threadIdx.x;
    if (e < E) {
        int pos = atomicAdd(&cursor[col[e]], 1);
        eds[pos] = make_int2(row[e], __float_as_int(ew[e]));
    }
}

// ---------- dinv[i] from CSR slice sum (no atomics); 4 lanes/node ----------
__global__ void dinv_kernel(const int* __restrict__ rowptr, const int2* __restrict__ eds,
                            const float* __restrict__ sumsq, float* __restrict__ dinv, int n) {
    int t = blockIdx.x * blockDim.x + threadIdx.x;
    int node = t >> 2, lane = t & 3;
    if (node >= n) return;
    int s = rowptr[node], e = rowptr[node + 1];
    float sum = 0.f;
    for (int i = s + lane; i < e; i += 4) sum += __int_as_float(eds[i].y);
    sum += __shfl_xor(sum, 1, 64);
    sum += __shfl_xor(sum, 2, 64);
    if (lane == 0) {
        float inv = 1.f / fmaxf(sqrtf(*sumsq), 1e-12f);
        float d = 1.f + sum * inv;
        dinv[node] = (d > 0.f) ? rsqrtf(d) : 0.f;
    }
}

// ---------- finalize eds[i].y = dinv[src] * ew_hat (in place) ----------
__global__ void coef_kernel(const float* __restrict__ dinv, const float* __restrict__ sumsq,
                            int2* __restrict__ eds, int E) {
    int i = blockIdx.x * blockDim.x + threadIdx.x;
    if (i < E) {
        float inv = 1.f / fmaxf(sqrtf(*sumsq), 1e-12f);
        int2 ed = eds[i];
        ed.y = __float_as_int(dinv[ed.x] * (__int_as_float(ed.y) * inv));
        eds[i] = ed;
    }
}

// ---------- GEMM: xw[n][128](bf16) = (relu?)in[n][128](f32) @ W[128][128] ----------
// Block: 64 rows x 64 cols (col half ch). LDS 65KB -> 2 blocks/CU.
template <bool RELU>
__global__ __launch_bounds__(256, 2) void gemm_kernel(const float* __restrict__ in,
                                                      const float* __restrict__ W,
                                                      ushort* __restrict__ out, int n) {
    __shared__ float xs[64 * 132];
    __shared__ float wl[128 * 64];
    const int rt = blockIdx.x >> 1;
    const int ch = blockIdx.x & 1;
    const int r0 = rt * 64;
    const float4* in4 = (const float4*)in;
    const float4* W4 = (const float4*)W;
#pragma unroll
    for (int i = 0; i < 8; ++i) {
        int idx = threadIdx.x + i * 256;
        int r = idx >> 5, q = idx & 31;
        float4 v = make_float4(0.f, 0.f, 0.f, 0.f);
        int rr = r0 + r;
        if (rr < n) v = in4[(size_t)rr * 32 + q];
        if (RELU) {
            v.x = fmaxf(v.x, 0.f); v.y = fmaxf(v.y, 0.f);
            v.z = fmaxf(v.z, 0.f); v.w = fmaxf(v.w, 0.f);
        }
        *(float4*)&xs[r * 132 + q * 4] = v;
        int k = idx >> 4, q2 = idx & 15;
        *(float4*)&wl[k * 64 + q2 * 4] = W4[(size_t)k * 32 + ch * 16 + q2];
    }
    __syncthreads();
    const int tx = threadIdx.x & 15;
    const int ty = threadIdx.x >> 4;
    float acc[4][4];
#pragma unroll
    for (int r = 0; r < 4; ++r)
#pragma unroll
        for (int c = 0; c < 4; ++c) acc[r][c] = 0.f;
    for (int k = 0; k < HID; k += 4) {
        float4 xv[4], wv[4];
#pragma unroll
        for (int r = 0; r < 4; ++r) xv[r] = *(const float4*)&xs[(ty * 4 + r) * 132 + k];
#pragma unroll
        for (int kk = 0; kk < 4; ++kk) wv[kk] = *(const float4*)&wl[(k + kk) * 64 + tx * 4];
#pragma unroll
        for (int r = 0; r < 4; ++r) {
            const float* xr = (const float*)&xv[r];
#pragma unroll
            for (int c = 0; c < 4; ++c) {
                acc[r][c] += xr[0] * ((const float*)&wv[0])[c]
                           + xr[1] * ((const float*)&wv[1])[c]
                           + xr[2] * ((const float*)&wv[2])[c]
                           + xr[3] * ((const float*)&wv[3])[c];
            }
        }
    }
#pragma unroll
    for (int r = 0; r < 4; ++r) {
        int rr = r0 + ty * 4 + r;
        if (rr < n) {
            uint2 o;
            o.x = pack_bf2(acc[r][0], acc[r][1]);
            o.y = pack_bf2(acc[r][2], acc[r][3]);
            *(uint2*)&out[(size_t)rr * HID + ch * 64 + tx * 4] = o;
        }
    }
}

// ---------- gather: h[c] = b + dinv[c]*(dinv[c]*xw[c] + sum_e coef[e]*xw[src[e]]) ----------
// xw is bf16. 16 lanes/node (8 feats each, 16B loads), 16 nodes per 256-block.
__global__ void gather_kernel(const int* __restrict__ rowptr, const int2* __restrict__ eds,
                              const ushort* __restrict__ xwh, const float* __restrict__ dinv,
                              const float* __restrict__ bias, float* __restrict__ h, int n) {
    int node = blockIdx.x * 16 + (threadIdx.x >> 4);
    if (node >= n) return;
    int q = threadIdx.x & 15;
    const uint4* xw4 = (const uint4*)xwh;   // 8 bf16 per uint4
    float dc = dinv[node];
    float acc[8];
    {
        uint4 a = xw4[(size_t)node * 16 + q];
        acc[0] = dc * bf_lo(a.x); acc[1] = dc * bf_hi(a.x);
        acc[2] = dc * bf_lo(a.y); acc[3] = dc * bf_hi(a.y);
        acc[4] = dc * bf_lo(a.z); acc[5] = dc * bf_hi(a.z);
        acc[6] = dc * bf_lo(a.w); acc[7] = dc * bf_hi(a.w);
    }
    int s = rowptr[node], e = rowptr[node + 1];
    int i = s;
    for (; i + 3 < e; i += 4) {
        int2 e0 = eds[i], e1 = eds[i + 1], e2 = eds[i + 2], e3 = eds[i + 3];
        float c0 = __int_as_float(e0.y), c1 = __int_as_float(e1.y);
        float c2 = __int_as_float(e2.y), c3 = __int_as_float(e3.y);
        uint4 v0 = xw4[(size_t)e0.x * 16 + q];
        uint4 v1 = xw4[(size_t)e1.x * 16 + q];
        uint4 v2 = xw4[(size_t)e2.x * 16 + q];
        uint4 v3 = xw4[(size_t)e3.x * 16 + q];
        acc[0] += c0 * bf_lo(v0.x) + c1 * bf_lo(v1.x) + c2 * bf_lo(v2.x) + c3 * bf_lo(v3.x);
        acc[1] += c0 * bf_hi(v0.x) + c1 * bf_hi(v1.x) + c2 * bf_hi(v2.x) + c3 * bf_hi(v3.x);
        acc[2] += c0 * bf_lo(v0.y) + c1 * bf_lo(v1.y) + c2 * bf_lo(v2.y) + c3 * bf_lo(v3.y);
        acc[3] += c0 * bf_hi(v0.y) + c1 * bf_hi(v1.y) + c2 * bf_hi(v2.y) + c3 * bf_hi(v3.y);
        acc[4] += c0 * bf_lo(v0.z) + c1 * bf_lo(v1.z) + c2 * bf_lo(v2.z) + c3 * bf_lo(v3.z);
        acc[5] += c0 * bf_hi(v0.z) + c1 * bf_hi(v1.z) + c2 * bf_hi(v2.z) + c3 * bf_hi(v3.z);
        acc[6] += c0 * bf_lo(v0.w) + c1 * bf_lo(v1.w) + c2 * bf_lo(v2.w) + c3 * bf_lo(v3.w);
        acc[7] += c0 * bf_hi(v0.w) + c1 * bf_hi(v1.w) + c2 * bf_hi(v2.w) + c3 * bf_hi(v3.w);
    }
    for (; i < e; ++i) {
        int2 ed = eds[i];
        float c = __int_as_float(ed.y);
        uint4 v = xw4[(size_t)ed.x * 16 + q];
        acc[0] += c * bf_lo(v.x); acc[1] += c * bf_hi(v.x);
        acc[2] += c * bf_lo(v.y); acc[3] += c * bf_hi(v.y);
        acc[4] += c * bf_lo(v.z); acc[5] += c * bf_hi(v.z);
        acc[6] += c * bf_lo(v.w); acc[7] += c * bf_hi(v.w);
    }
    const float4* b4 = (const float4*)(bias + q * 8);
    float4 bb0 = b4[0], bb1 = b4[1];
    float* hp = h + (size_t)node * HID + q * 8;
    float4 o0 = make_float4(bb0.x + dc * acc[0], bb0.y + dc * acc[1],
                            bb0.z + dc * acc[2], bb0.w + dc * acc[3]);
    float4 o1 = make_float4(bb1.x + dc * acc[4], bb1.y + dc * acc[5],
                            bb1.z + dc * acc[6], bb1.w + dc * acc[7]);
    *(float4*)hp = o0;
    *(float4*)(hp + 4) = o1;
}

// ---------- segment_max pool (relu fused: 0-init + max with raw h) ----------
__global__ void pool_kernel(const float* __restrict__ h, const int* __restrict__ batch,
                            int n, unsigned* __restrict__ pooled) {
    int f = threadIdx.x;
    int n0 = blockIdx.x * 64;
    int n1 = min(n0 + 64, n);
    int cur = -1;
    float m = 0.f;
    for (int i = n0; i < n1; ++i) {
        int g = batch[i];
        if (g != cur) {
            if (cur >= 0) atomicMax(&pooled[cur * HID + f], __float_as_uint(m));
            cur = g;
            m = 0.f;
        }
        m = fmaxf(m, h[i * HID + f]);
    }
    if (cur >= 0) atomicMax(&pooled[cur * HID + f], __float_as_uint(m));
}

// ---------- final: out[g][c] = pooled[g] . Wl[:,c] + bl[c] ----------
__global__ void final_kernel(const unsigned* __restrict__ pooled, const float* __restrict__ Wl,
                             const float* __restrict__ bl, float* __restrict__ out) {
    __shared__ float p[HID];
    int g = blockIdx.x;
    p[threadIdx.x] = __uint_as_float(pooled[g * HID + threadIdx.x]);
    __syncthreads();
    if (threadIdx.x < NCLS) {
        float acc = bl[threadIdx.x];
        for (int f = 0; f < HID; ++f) acc += p[f] * Wl[f * NCLS + threadIdx.x];
        out[g * NCLS + threadIdx.x] = acc;
    }
}

extern "C" void kernel_launch(void* const* d_in, const int* in_sizes, int n_in,
                              void* d_out, int out_size, void* d_ws, size_t ws_size,
                              hipStream_t stream) {
    const float* x     = (const float*)d_in[0];
    const int*   ei    = (const int*)d_in[1];
    const float* ew    = (const float*)d_in[2];
    const int*   batch = (const int*)d_in[3];
    const float* W1 = (const float*)d_in[4];
    const float* b1 = (const float*)d_in[5];
    const float* W2 = (const float*)d_in[6];
    const float* b2 = (const float*)d_in[7];
    const float* W3 = (const float*)d_in[8];
    const float* b3 = (const float*)d_in[9];
    const float* Wl = (const float*)d_in[10];
    const float* bl = (const float*)d_in[11];

    const int E = in_sizes[2];
    const int n = in_sizes[3];
    const int* row = ei;
    const int* col = ei + E;
    const int npad = 50048;

    float* ws = (float*)d_ws;
    size_t off = 0;
    float* sumsq = ws + off; off += 64;
    float* dinv  = ws + off; off += npad;
    int*   cnt   = (int*)(ws + off); off += npad;     // reused as cursor after scan
    int*   rowptr= (int*)(ws + off); off += npad + 64;
    int*   bsums = (int*)(ws + off); off += 512;
    int2*  eds   = (int2*)(ws + off); off += 2 * (size_t)E;   // packed {src, coef}
    ushort* xwh  = (ushort*)(ws + off); off += (size_t)n * HID / 2;  // bf16 xw
    float* bufB  = ws + off; off += (size_t)n * HID;  // h (f32)
    unsigned* pooled = (unsigned*)(ws + off); off += NGRAPH * HID;
    int* partial = (int*)bufB;   // alias: scan completes before first gather writes bufB

    hipMemsetAsync(sumsq, 0, sizeof(float), stream);
    hipMemsetAsync(cnt, 0, (size_t)n * sizeof(int), stream);
    hipMemsetAsync(pooled, 0, NGRAPH * HID * sizeof(float), stream);

    const int nb = (n + 255) / 256;
    const int eg = (E + 255) / 256;

    sumsq_kernel<<<512, 256, 0, stream>>>(ew, E, sumsq);
    hist_kernel<<<eg, 256, 0, stream>>>(col, E, cnt);
    scan1_kernel<<<nb, 256, 0, stream>>>(cnt, n, partial, bsums);
    scan2_kernel<<<1, 256, 0, stream>>>(bsums, nb);
    scan3_kernel<<<nb, 256, 0, stream>>>(partial, bsums, rowptr, cnt /*cursor*/, n, E);
    build_csr_kernel<<<eg, 256, 0, stream>>>(row, col, ew, cnt /*cursor*/, eds, E);
    dinv_kernel<<<(4 * n + 255) / 256, 256, 0, stream>>>(rowptr, eds, sumsq, dinv, n);
    coef_kernel<<<eg, 256, 0, stream>>>(dinv, sumsq, eds, E);

    const int gemm_grid = ((n + 63) / 64) * 2;
    const int gath_grid = (n + 15) / 16;

    // layer 1
    gemm_kernel<false><<<gemm_grid, 256, 0, stream>>>(x, W1, xwh, n);
    gather_kernel<<<gath_grid, 256, 0, stream>>>(rowptr, eds, xwh, dinv, b1, bufB, n);
    // layer 2
    gemm_kernel<true><<<gemm_grid, 256, 0, stream>>>(bufB, W2, xwh, n);
    gather_kernel<<<gath_grid, 256, 0, stream>>>(rowptr, eds, xwh, dinv, b2, bufB, n);
    // layer 3
    gemm_kernel<true><<<gemm_grid, 256, 0, stream>>>(bufB, W3, xwh, n);
    gather_kernel<<<gath_grid, 256, 0, stream>>>(rowptr, eds, xwh, dinv, b3, bufB, n);

    // pool (relu fused via 0-init) + head
    pool_kernel<<<(n + 63) / 64, HID, 0, stream>>>(bufB, batch, n, pooled);
    final_kernel<<<NGRAPH, HID, 0, stream>>>(pooled, Wl, bl, (float*)d_out);
}